// Round 10
// baseline (312.841 us; speedup 1.0000x reference)
//
#include <hip/hip_runtime.h>
#include <hip/hip_bf16.h>

#define BB 4
#define TT 2048
#define DDIM 1024
#define HH 16
#define HD 64

typedef __bf16 bf16_t;
typedef __bf16 bf16x4 __attribute__((ext_vector_type(4)));
typedef __bf16 bf16x8 __attribute__((ext_vector_type(8)));
typedef float f32x4 __attribute__((ext_vector_type(4)));

#define GLOAD_LDS(gp, lp) \
    __builtin_amdgcn_global_load_lds( \
        (const __attribute__((address_space(1))) void*)(gp), \
        (__attribute__((address_space(3))) void*)(lp), 16, 0, 0)

// ---------------------------------------------------------------------------
// fp32 -> bf16 conversion, 8 elems/thread, grid-stride. n8 = n/8.
// ---------------------------------------------------------------------------
__global__ __launch_bounds__(256) void cvt_f32_bf16(
    const float* __restrict__ src, bf16_t* __restrict__ dst, size_t n8)
{
    size_t i = (size_t)blockIdx.x * blockDim.x + threadIdx.x;
    const size_t stride = (size_t)gridDim.x * blockDim.x;
    for (; i < n8; i += stride) {
        const f32x4 a = ((const f32x4*)src)[2 * i];
        const f32x4 b = ((const f32x4*)src)[2 * i + 1];
        bf16x8 v;
#pragma unroll
        for (int j = 0; j < 4; j++) { v[j] = (bf16_t)a[j]; v[4 + j] = (bf16_t)b[j]; }
        ((bf16x8*)dst)[i] = v;
    }
}

// Pack 4 fp32 weight matrices into one bf16 buffer [wq|wk|wv|wo].
__global__ __launch_bounds__(256) void cvt_wpack(
    const float* __restrict__ s0, const float* __restrict__ s1,
    const float* __restrict__ s2, const float* __restrict__ s3,
    bf16_t* __restrict__ dst)
{
    const size_t n8 = (size_t)4 * DDIM * DDIM / 8;
    size_t i = (size_t)blockIdx.x * blockDim.x + threadIdx.x;
    const size_t stride = (size_t)gridDim.x * blockDim.x;
    for (; i < n8; i += stride) {
        const int sel = (int)(i >> 17);
        const float* s = sel == 0 ? s0 : sel == 1 ? s1 : sel == 2 ? s2 : s3;
        const size_t off8 = i & ((1u << 17) - 1);
        const f32x4 a = ((const f32x4*)s)[2 * off8];
        const f32x4 b = ((const f32x4*)s)[2 * off8 + 1];
        bf16x8 v;
#pragma unroll
        for (int j = 0; j < 4; j++) { v[j] = (bf16_t)a[j]; v[4 + j] = (bf16_t)b[j]; }
        ((bf16x8*)dst)[i] = v;
    }
}

// ---------------------------------------------------------------------------
// BK=64 FULL-row XOR staging. global_load_lds writes linearly (base +
// lane*16B), so the GLOBAL source chunk is pre-permuted: LDS(row, j) =
// G(row, j ^ (row&7)) at 8-elem chunk granularity. Reads un-XOR with
// (row&7) == (l15&7) on every fragment row -> conflict-free (verified r5:
// SQ_LDS_BANK_CONFLICT 1.9e7 -> 0).
// Stages 8 rows per instruction: lane -> row lane>>3, chunk lane&7.
// ---------------------------------------------------------------------------
__device__ __forceinline__ void stage8(const bf16_t* __restrict__ g, int ld,
                                       bf16_t* __restrict__ ldsbase, int lane)
{
    const int rr = lane >> 3;
    const int cc = (lane & 7) ^ rr;
    GLOAD_LDS(&g[(size_t)rr * ld + cc * 8], ldsbase);
}

// ---------------------------------------------------------------------------
// Fused QKV GEMM v7 (r7-proven, unchanged): counted-vmcnt 3-buffer +
// m201-style phase-locked schedule. 256x128 tile, BK=64, 512 thr, 144 KiB.
// Per K-tile: 2 phases of {8 ds_read -> 3 gload_lds -> s_barrier ->
// lgkmcnt(0)+sched_barrier -> setprio(1) 16 MFMA setprio(0) -> s_barrier};
// tile boundary s_waitcnt vmcnt(6) (tail 0) + s_barrier.
// T1 XCD swizzle; Q-region epilogue pre-scales by 0.125*log2e.
// ---------------------------------------------------------------------------
__global__ __launch_bounds__(512) void gemm_qkv(
    const bf16_t* __restrict__ A, const bf16_t* __restrict__ Wqkv,
    bf16_t* __restrict__ Qo, bf16_t* __restrict__ Ko, bf16_t* __restrict__ Vto,
    int M, int K)
{
    __shared__ alignas(16) bf16_t As[3][256 * 64];
    __shared__ alignas(16) bf16_t Bs[3][128 * 64];

    const int tid  = threadIdx.x;
    const int lane = tid & 63;
    const int w    = tid >> 6;          // 0..7
    const int quad = lane >> 4;
    const int l15  = lane & 15;
    const int wm   = (w >> 1) * 64;     // 0/64/128/192
    const int wn   = (w & 1) * 64;      // 0/64

    // T1 XCD swizzle: hw linear id -> contiguous chunk per XCD (768 %8==0)
    const int nwg = gridDim.x * gridDim.y;
    const int cpx = nwg >> 3;
    int id = blockIdx.y * gridDim.x + blockIdx.x;
    id = (id & 7) * cpx + (id >> 3);
    const int tileN = (id % 24) * 128;     // gridDim.x == 24 in both paths
    const int tileM = (id / 24) * 256;

    const f32x4 vzero = {0.f, 0.f, 0.f, 0.f};
    f32x4 acc[4][4];
#pragma unroll
    for (int i = 0; i < 4; i++)
#pragma unroll
        for (int j = 0; j < 4; j++) acc[i][j] = vzero;

    const int par8 = l15 & 7;            // read-side un-XOR (row&7 == l15&7)

#define STAGE_HALF(t_, b_, p_) do { \
        const int k0_ = (t_) << 6; \
        _Pragma("unroll") \
        for (int q_ = 2 * (p_); q_ < 2 * (p_) + 2; q_++) { \
            const int r0_ = w * 32 + q_ * 8; \
            stage8(&A[(size_t)(tileM + r0_) * K + k0_], K, \
                   &As[b_][r0_ * 64], lane); \
        } \
        { \
            const int r0_ = w * 16 + (p_) * 8; \
            stage8(&Wqkv[(size_t)(tileN + r0_) * K + k0_], K, \
                   &Bs[b_][r0_ * 64], lane); \
        } \
    } while (0)

    // prologue: tiles 0 and 1 fully in flight (12 loads/thread)
    STAGE_HALF(0, 0, 0); STAGE_HALF(0, 0, 1);
    STAGE_HALF(1, 1, 0); STAGE_HALF(1, 1, 1);

    const int NT = K >> 6;               // 16
#pragma unroll 1
    for (int t = 0; t < NT; ++t) {
        if (t + 1 < NT) asm volatile("s_waitcnt vmcnt(6)" ::: "memory");
        else            asm volatile("s_waitcnt vmcnt(0)" ::: "memory");
        __builtin_amdgcn_s_barrier();
        asm volatile("" ::: "memory");   // compiler fence: no read hoisting

        const bf16_t* as = &As[t % 3][0];
        const bf16_t* bs = &Bs[t % 3][0];
        const int nb = (t + 2) % 3;

#pragma unroll
        for (int p = 0; p < 2; p++) {
            const int phys = ((p * 4 + quad) ^ par8) << 3;
            bf16x8 af[4], bf[4];
#pragma unroll
            for (int i = 0; i < 4; i++)
                af[i] = *(bf16x8*)&as[(wm + i * 16 + l15) * 64 + phys];
#pragma unroll
            for (int j = 0; j < 4; j++)
                bf[j] = *(bf16x8*)&bs[(wn + j * 16 + l15) * 64 + phys];
            if (t + 2 < NT) STAGE_HALF(t + 2, nb, p);
            __builtin_amdgcn_s_barrier();
            asm volatile("s_waitcnt lgkmcnt(0)" ::: "memory");
            __builtin_amdgcn_sched_barrier(0);
            __builtin_amdgcn_s_setprio(1);
#pragma unroll
            for (int i = 0; i < 4; i++)
#pragma unroll
                for (int j = 0; j < 4; j++)
                    acc[i][j] = __builtin_amdgcn_mfma_f32_16x16x32_bf16(
                        af[i], bf[j], acc[i][j], 0, 0, 0);
            __builtin_amdgcn_s_setprio(0);
            if (p == 0) __builtin_amdgcn_s_barrier();
        }
    }
#undef STAGE_HALF

    const int region = tileN >> 10;    // 0=Q, 1=K, 2=V (block-uniform)
    const float osc = (region == 0) ? 0.125f * 1.44269504f : 1.0f;
#pragma unroll
    for (int i = 0; i < 4; i++) {
        const int row = tileM + wm + i * 16 + quad * 4;
#pragma unroll
        for (int j = 0; j < 4; j++) {
            const int ncol = tileN + wn + j * 16 + l15;
            if (region == 2) {
                const int cl = ncol - 2048;
                const int h = cl >> 6, d = cl & 63;
                const int bb = row >> 11, tloc = row & (TT - 1);
                bf16x4 pk;
#pragma unroll
                for (int r = 0; r < 4; r++) pk[r] = (bf16_t)acc[i][j][r];
                *(bf16x4*)&Vto[(((size_t)bb * HH + h) * HD + d) * TT + tloc] = pk;
            } else {
                bf16_t* dst = (region == 0) ? Qo : Ko;
                const int cl = ncol & 1023;
#pragma unroll
                for (int r = 0; r < 4; r++)
                    dst[(size_t)(row + r) * DDIM + cl] = (bf16_t)(acc[i][j][r] * osc);
            }
        }
    }
}

// ---------------------------------------------------------------------------
// Output-projection GEMM v3 (r5-proven, unchanged): 128x128 tile, 2-phase
// double-buffer, full-row XOR swizzle, fp32 epilogue. Grid (8, M/128).
// ---------------------------------------------------------------------------
__global__ __launch_bounds__(256) void gemm_out(
    const bf16_t* __restrict__ A, const bf16_t* __restrict__ Bm,
    float* __restrict__ C, int M, int N, int K)
{
    __shared__ alignas(16) bf16_t As[2][128 * 64];
    __shared__ alignas(16) bf16_t Bs[2][128 * 64];

    const int tid  = threadIdx.x;
    const int lane = tid & 63;
    const int w    = tid >> 6;
    const int quad = lane >> 4;
    const int l15  = lane & 15;
    const int wm   = (w >> 1) * 64;
    const int wn   = (w & 1) * 64;

    const int nwg = gridDim.x * gridDim.y;
    const int cpx = nwg >> 3;
    int id = blockIdx.y * gridDim.x + blockIdx.x;
    id = (id & 7) * cpx + (id >> 3);
    const int tileN = (id % 8) * 128;      // gridDim.x == 8
    const int tileM = (id / 8) * 128;

    const f32x4 vzero = {0.f, 0.f, 0.f, 0.f};
    f32x4 acc[4][4];
#pragma unroll
    for (int i = 0; i < 4; i++)
#pragma unroll
        for (int j = 0; j < 4; j++) acc[i][j] = vzero;

    const int par8 = l15 & 7;

#pragma unroll
    for (int q = 0; q < 4; q++) {
        const int r0 = w * 32 + q * 8;
        stage8(&A[(size_t)(tileM + r0) * K], K, &As[0][r0 * 64], lane);
        stage8(&Bm[(size_t)(tileN + r0) * K], K, &Bs[0][r0 * 64], lane);
    }
    __syncthreads();

    const int NT = K >> 6;
    for (int t = 0; t < NT; ++t) {
        const int cur = t & 1;
        if (t + 1 < NT) {
            const int k0 = (t + 1) << 6;
#pragma unroll
            for (int q = 0; q < 4; q++) {
                const int r0 = w * 32 + q * 8;
                stage8(&A[(size_t)(tileM + r0) * K + k0], K,
                       &As[cur ^ 1][r0 * 64], lane);
                stage8(&Bm[(size_t)(tileN + r0) * K + k0], K,
                       &Bs[cur ^ 1][r0 * 64], lane);
            }
        }

#pragma unroll
        for (int ss = 0; ss < 2; ss++) {
            const int phys = ((ss * 4 + quad) ^ par8) << 3;
            bf16x8 af[4], bf[4];
#pragma unroll
            for (int i = 0; i < 4; i++)
                af[i] = *(bf16x8*)&As[cur][(wm + i * 16 + l15) * 64 + phys];
#pragma unroll
            for (int j = 0; j < 4; j++)
                bf[j] = *(bf16x8*)&Bs[cur][(wn + j * 16 + l15) * 64 + phys];
            __builtin_amdgcn_s_setprio(1);
#pragma unroll
            for (int i = 0; i < 4; i++)
#pragma unroll
                for (int j = 0; j < 4; j++)
                    acc[i][j] = __builtin_amdgcn_mfma_f32_16x16x32_bf16(
                        af[i], bf[j], acc[i][j], 0, 0, 0);
            __builtin_amdgcn_s_setprio(0);
        }
        __syncthreads();
    }

#pragma unroll
    for (int i = 0; i < 4; i++) {
#pragma unroll
        for (int r = 0; r < 4; r++) {
            const int row = tileM + wm + i * 16 + quad * 4 + r;
#pragma unroll
            for (int j = 0; j < 4; j++)
                C[(size_t)row * N + tileN + wn + j * 16 + l15] = acc[i][j][r];
        }
    }
}

// ---------------------------------------------------------------------------
// Flash causal attention v11: TLP-scaled. One 128-row strip per block
// (pairing dropped), grid (nbh, 16) = 1024 blocks; single-buffer Ks/Vt
// (2 barriers/tile) -> LDS 34 KiB -> 4 blocks/CU = 16 waves/CU (2x TLP;
// v10 grid supplied only 2 blocks/CU, Occupancy 19%). Longest-first
// dispatch (strip = 15 - blockIdx.y) so the 32-tile blocks start first and
// short blocks fill the scheduling tail. Per-bh staging volume unchanged
// (sum(2s+2) = 272 tiles = old 8x34). XCD locality kept: linear id mod 8 =
// bh mod 8. T14 reg prefetch + full row&7 XOR (conflict-free) + setprio +
// pre-folded scale retained. Y aliases Q (block touches only its strip).
// ---------------------------------------------------------------------------
__global__ __launch_bounds__(256, 4) void attn_causal(
    const bf16_t* __restrict__ Q, const bf16_t* __restrict__ Kg,
    const bf16_t* __restrict__ Vt_g, bf16_t* __restrict__ Y)
{
    __shared__ alignas(16) bf16_t Ks[64 * 64];     // [key][d] XOR-swz
    __shared__ alignas(16) bf16_t Vt[64 * 64];     // [d][key] XOR-swz
    __shared__ alignas(16) bf16_t Ps[4][32 * 72];  // per-wave P, chunk-swz

    const int tid  = threadIdx.x;
    const int lane = tid & 63;
    const int w    = tid >> 6;
    const int quad = lane >> 4;
    const int l15  = lane & 15;
    const int bh   = blockIdx.x;
    const int strip = 15 - blockIdx.y;   // longest strips dispatch first
    const int b = bh >> 4, h = bh & 15;

    const int stg_row = tid >> 3;        // 0..31
    const int stg_c8  = (tid & 7) * 8;
    const int stg_off = stg_row * 64 + ((((tid & 7) ^ (stg_row & 7))) << 3);
    const int par8 = l15 & 7;            // read-side un-XOR

    const f32x4 vzero = {0.f, 0.f, 0.f, 0.f};
    bf16x8 ones;
#pragma unroll
    for (int j = 0; j < 8; j++) ones[j] = (l15 == 0) ? (bf16_t)1.0f : (bf16_t)0.0f;

    const bf16_t* kg0 = &Kg[(size_t)(b * TT + stg_row) * DDIM + h * 64 + stg_c8];
    const bf16_t* vg0 = &Vt_g[((size_t)bh * HD + stg_row) * TT + stg_c8];

    const int qbase = strip * 128;

    bf16x8 qf[2][2];
#pragma unroll
    for (int mi = 0; mi < 2; mi++) {
        const size_t rq =
            (size_t)(b * TT + qbase + w * 32 + mi * 16 + l15) * DDIM + h * 64;
        qf[mi][0] = *(const bf16x8*)&Q[rq + quad * 8];
        qf[mi][1] = *(const bf16x8*)&Q[rq + 32 + quad * 8];
    }

    f32x4 o[2][4], o4[2];
#pragma unroll
    for (int mi = 0; mi < 2; mi++) {
#pragma unroll
        for (int c = 0; c < 4; c++) o[mi][c] = vzero;
        o4[mi] = vzero;
    }

    const int nkt = 2 * strip + 2;

    // T14 prologue: prefetch key-tile 0 into registers
    bf16x8 kreg[2], vreg[2];
#pragma unroll
    for (int p = 0; p < 2; p++) {
        kreg[p] = *(const bf16x8*)&kg0[(size_t)(p * 32) * DDIM];
        vreg[p] = *(const bf16x8*)&vg0[(size_t)(p * 32) * TT];
    }

#pragma unroll 1
    for (int kt = 0; kt < nkt; kt++) {
        const int kbase = kt * 64;
        __syncthreads();                 // readers of prev tile done
#pragma unroll
        for (int p = 0; p < 2; p++) {
            *(bf16x8*)&Ks[stg_off + p * 32 * 64] = kreg[p];
            *(bf16x8*)&Vt[stg_off + p * 32 * 64] = vreg[p];
        }
        if (kt + 1 < nkt) {
            const int nb = (kt + 1) * 64;
#pragma unroll
            for (int p = 0; p < 2; p++) {
                kreg[p] = *(const bf16x8*)&kg0[(size_t)(nb + p * 32) * DDIM];
                vreg[p] = *(const bf16x8*)&vg0[(size_t)(p * 32) * TT + nb];
            }
        }
        __syncthreads();                 // writes visible

        // S = Q·K^T : shared kf reads across both m-fragments
        f32x4 s[2][4];
        __builtin_amdgcn_s_setprio(1);
#pragma unroll
        for (int c = 0; c < 4; c++) {
            const int krow = (c * 16 + l15) * 64;
            bf16x8 kf0 = *(bf16x8*)&Ks[krow + ((quad ^ par8) << 3)];
            bf16x8 kf1 = *(bf16x8*)&Ks[krow + (((4 + quad) ^ par8) << 3)];
#pragma unroll
            for (int mi = 0; mi < 2; mi++) {
                f32x4 t = __builtin_amdgcn_mfma_f32_16x16x32_bf16(
                    qf[mi][0], kf0, vzero, 0, 0, 0);
                s[mi][c] = __builtin_amdgcn_mfma_f32_16x16x32_bf16(
                    qf[mi][1], kf1, t, 0, 0, 0);
            }
        }
        __builtin_amdgcn_s_setprio(0);

        // p = exp2(s) (scale pre-folded into Q); mask near the diagonal
#pragma unroll
        for (int mi = 0; mi < 2; mi++) {
            const int qlow = qbase + w * 32 + mi * 16;
            const bool need = (kbase + 63 > qlow);   // wave-uniform
#pragma unroll
            for (int r = 0; r < 4; r++) {
                const int qrow = qlow + quad * 4 + r;
                const int prow = mi * 16 + quad * 4 + r;
#pragma unroll
                for (int c = 0; c < 4; c++) {
                    float sv = s[mi][c][r];
                    if (need && (kbase + c * 16 + l15 > qrow)) sv = -1e30f;
                    const int pchunk = (c * 2 + (l15 >> 3)) ^ (prow >> 2);
                    Ps[w][prow * 72 + (pchunk << 3) + (l15 & 7)] =
                        (bf16_t)__builtin_amdgcn_exp2f(sv);
                }
            }
        }
        // Ps wave-private: same-wave RAW via lgkmcnt, no barrier.

        // O += P·V ; o4 += P·ones
        __builtin_amdgcn_s_setprio(1);
#pragma unroll
        for (int ss = 0; ss < 2; ss++) {
            bf16x8 pf[2];
#pragma unroll
            for (int mi = 0; mi < 2; mi++) {
                const int m = mi * 16 + l15;
                pf[mi] = *(bf16x8*)&Ps[w][m * 72 +
                                          ((((ss * 4 + quad) ^ (m >> 2)) & 7) << 3)];
            }
#pragma unroll
            for (int c = 0; c < 4; c++) {
                bf16x8 vf = *(bf16x8*)&Vt[(c * 16 + l15) * 64 +
                                          (((ss * 4 + quad) ^ par8) << 3)];
#pragma unroll
                for (int mi = 0; mi < 2; mi++)
                    o[mi][c] = __builtin_amdgcn_mfma_f32_16x16x32_bf16(
                        pf[mi], vf, o[mi][c], 0, 0, 0);
            }
#pragma unroll
            for (int mi = 0; mi < 2; mi++)
                o4[mi] = __builtin_amdgcn_mfma_f32_16x16x32_bf16(
                    pf[mi], ones, o4[mi], 0, 0, 0);
        }
        __builtin_amdgcn_s_setprio(0);
    }

    // epilogue: row-sum lives in lane l15==0 of each quad group
#pragma unroll
    for (int mi = 0; mi < 2; mi++) {
#pragma unroll
        for (int r = 0; r < 4; r++) {
            const float lsum = __shfl(o4[mi][r], lane & 48, 64);
            const float inv = 1.0f / lsum;
            const int q = qbase + w * 32 + mi * 16 + quad * 4 + r;
#pragma unroll
            for (int c = 0; c < 4; c++)
                Y[(size_t)(b * TT + q) * DDIM + h * 64 + c * 16 + l15] =
                    (bf16_t)(o[mi][c][r] * inv);
        }
    }
}

extern "C" void kernel_launch(void* const* d_in, const int* in_sizes, int n_in,
                              void* d_out, int out_size, void* d_ws, size_t ws_size,
                              hipStream_t stream) {
    (void)in_sizes; (void)n_in; (void)out_size;
    const float* x  = (const float*)d_in[0];
    float* out = (float*)d_out;

    const int M = BB * TT;                     // 8192
    const size_t REGION = (size_t)M * DDIM;    // 8M elems
    const size_t WREG   = (size_t)DDIM * DDIM; // 1M elems
    const size_t BATCH  = (size_t)TT * DDIM;   // 2M elems
    bf16_t* ws = (bf16_t*)d_ws;

    if (ws_size >= (72ull << 20)) {
        // Full path: xb(8M) wpk(4M) Qb(8M) Kb(8M) Vtb(8M) = 36M bf16 = 72 MiB.
        bf16_t* xb  = ws;
        bf16_t* wpk = ws + REGION;
        bf16_t* Qb  = wpk + 4 * WREG;
        bf16_t* Kb  = Qb + REGION;
        bf16_t* Vtb = Kb + REGION;

        cvt_f32_bf16<<<1024, 256, 0, stream>>>(x, xb, REGION / 8);
        cvt_wpack<<<512, 256, 0, stream>>>(
            (const float*)d_in[1], (const float*)d_in[2],
            (const float*)d_in[3], (const float*)d_in[4], wpk);

        gemm_qkv<<<dim3(24, M / 256), 512, 0, stream>>>(
            xb, wpk, Qb, Kb, Vtb, M, DDIM);
        attn_causal<<<dim3(BB * HH, 16), 256, 0, stream>>>(Qb, Kb, Vtb, Qb);
        gemm_out<<<dim3(8, M / 128), 256, 0, stream>>>(
            Qb, wpk + 3 * WREG, out, M, DDIM, DDIM);
    } else {
        // Per-batch path: wpk(4M) + xb(2M) + Qb,Kb,Vtb(3x2M) = 12M = 24 MiB.
        bf16_t* wpk = ws;
        bf16_t* xbb = ws + 4 * WREG;
        bf16_t* Qb  = xbb + BATCH;
        bf16_t* Kb  = Qb + BATCH;
        bf16_t* Vtb = Kb + BATCH;

        cvt_wpack<<<512, 256, 0, stream>>>(
            (const float*)d_in[1], (const float*)d_in[2],
            (const float*)d_in[3], (const float*)d_in[4], wpk);

        for (int b = 0; b < BB; b++) {
            const float* x_b = x + (size_t)b * BATCH;
            float* out_b = out + (size_t)b * BATCH;
            cvt_f32_bf16<<<512, 256, 0, stream>>>(x_b, xbb, BATCH / 8);
            gemm_qkv<<<dim3(24, TT / 256), 512, 0, stream>>>(
                xbb, wpk, Qb, Kb, Vtb, TT, DDIM);
            attn_causal<<<dim3(HH, 16), 256, 0, stream>>>(Qb, Kb, Vtb, Qb);
            gemm_out<<<dim3(8, TT / 128), 256, 0, stream>>>(
                Qb, wpk + 3 * WREG, out_b, TT, DDIM, DDIM);
        }
    }
}

// Round 11
// 243.106 us; speedup vs baseline: 1.2869x; 1.2869x over previous
//
#include <hip/hip_runtime.h>
#include <hip/hip_bf16.h>

#define BB 4
#define TT 2048
#define DDIM 1024
#define HH 16
#define HD 64

typedef __bf16 bf16_t;
typedef __bf16 bf16x4 __attribute__((ext_vector_type(4)));
typedef __bf16 bf16x8 __attribute__((ext_vector_type(8)));
typedef float f32x4 __attribute__((ext_vector_type(4)));

#define GLOAD_LDS(gp, lp) \
    __builtin_amdgcn_global_load_lds( \
        (const __attribute__((address_space(1))) void*)(gp), \
        (__attribute__((address_space(3))) void*)(lp), 16, 0, 0)

// ---------------------------------------------------------------------------
// fp32 -> bf16 conversion, 8 elems/thread, grid-stride. n8 = n/8.
// ---------------------------------------------------------------------------
__global__ __launch_bounds__(256) void cvt_f32_bf16(
    const float* __restrict__ src, bf16_t* __restrict__ dst, size_t n8)
{
    size_t i = (size_t)blockIdx.x * blockDim.x + threadIdx.x;
    const size_t stride = (size_t)gridDim.x * blockDim.x;
    for (; i < n8; i += stride) {
        const f32x4 a = ((const f32x4*)src)[2 * i];
        const f32x4 b = ((const f32x4*)src)[2 * i + 1];
        bf16x8 v;
#pragma unroll
        for (int j = 0; j < 4; j++) { v[j] = (bf16_t)a[j]; v[4 + j] = (bf16_t)b[j]; }
        ((bf16x8*)dst)[i] = v;
    }
}

// Pack 4 fp32 weight matrices into one bf16 buffer [wq|wk|wv|wo].
__global__ __launch_bounds__(256) void cvt_wpack(
    const float* __restrict__ s0, const float* __restrict__ s1,
    const float* __restrict__ s2, const float* __restrict__ s3,
    bf16_t* __restrict__ dst)
{
    const size_t n8 = (size_t)4 * DDIM * DDIM / 8;
    size_t i = (size_t)blockIdx.x * blockDim.x + threadIdx.x;
    const size_t stride = (size_t)gridDim.x * blockDim.x;
    for (; i < n8; i += stride) {
        const int sel = (int)(i >> 17);
        const float* s = sel == 0 ? s0 : sel == 1 ? s1 : sel == 2 ? s2 : s3;
        const size_t off8 = i & ((1u << 17) - 1);
        const f32x4 a = ((const f32x4*)s)[2 * off8];
        const f32x4 b = ((const f32x4*)s)[2 * off8 + 1];
        bf16x8 v;
#pragma unroll
        for (int j = 0; j < 4; j++) { v[j] = (bf16_t)a[j]; v[4 + j] = (bf16_t)b[j]; }
        ((bf16x8*)dst)[i] = v;
    }
}

// ---------------------------------------------------------------------------
// BK=64 FULL-row XOR staging. global_load_lds writes linearly (base +
// lane*16B), so the GLOBAL source chunk is pre-permuted: LDS(row, j) =
// G(row, j ^ (row&7)) at 8-elem chunk granularity. Reads un-XOR with
// (row&7) == (l15&7) on every fragment row -> conflict-free (verified r5:
// SQ_LDS_BANK_CONFLICT 1.9e7 -> 0).
// Stages 8 rows per instruction: lane -> row lane>>3, chunk lane&7.
// ---------------------------------------------------------------------------
__device__ __forceinline__ void stage8(const bf16_t* __restrict__ g, int ld,
                                       bf16_t* __restrict__ ldsbase, int lane)
{
    const int rr = lane >> 3;
    const int cc = (lane & 7) ^ rr;
    GLOAD_LDS(&g[(size_t)rr * ld + cc * 8], ldsbase);
}

// ---------------------------------------------------------------------------
// Fused QKV GEMM v7 (r7-proven, unchanged): counted-vmcnt 3-buffer +
// m201-style phase-locked schedule. 256x128 tile, BK=64, 512 thr, 144 KiB.
// Per K-tile: 2 phases of {8 ds_read -> 3 gload_lds -> s_barrier ->
// lgkmcnt(0)+sched_barrier -> setprio(1) 16 MFMA setprio(0) -> s_barrier};
// tile boundary s_waitcnt vmcnt(6) (tail 0) + s_barrier.
// T1 XCD swizzle; Q-region epilogue pre-scales by 0.125*log2e.
// ---------------------------------------------------------------------------
__global__ __launch_bounds__(512) void gemm_qkv(
    const bf16_t* __restrict__ A, const bf16_t* __restrict__ Wqkv,
    bf16_t* __restrict__ Qo, bf16_t* __restrict__ Ko, bf16_t* __restrict__ Vto,
    int M, int K)
{
    __shared__ alignas(16) bf16_t As[3][256 * 64];
    __shared__ alignas(16) bf16_t Bs[3][128 * 64];

    const int tid  = threadIdx.x;
    const int lane = tid & 63;
    const int w    = tid >> 6;          // 0..7
    const int quad = lane >> 4;
    const int l15  = lane & 15;
    const int wm   = (w >> 1) * 64;     // 0/64/128/192
    const int wn   = (w & 1) * 64;      // 0/64

    // T1 XCD swizzle: hw linear id -> contiguous chunk per XCD (768 %8==0)
    const int nwg = gridDim.x * gridDim.y;
    const int cpx = nwg >> 3;
    int id = blockIdx.y * gridDim.x + blockIdx.x;
    id = (id & 7) * cpx + (id >> 3);
    const int tileN = (id % 24) * 128;     // gridDim.x == 24 in both paths
    const int tileM = (id / 24) * 256;

    const f32x4 vzero = {0.f, 0.f, 0.f, 0.f};
    f32x4 acc[4][4];
#pragma unroll
    for (int i = 0; i < 4; i++)
#pragma unroll
        for (int j = 0; j < 4; j++) acc[i][j] = vzero;

    const int par8 = l15 & 7;            // read-side un-XOR (row&7 == l15&7)

#define STAGE_HALF(t_, b_, p_) do { \
        const int k0_ = (t_) << 6; \
        _Pragma("unroll") \
        for (int q_ = 2 * (p_); q_ < 2 * (p_) + 2; q_++) { \
            const int r0_ = w * 32 + q_ * 8; \
            stage8(&A[(size_t)(tileM + r0_) * K + k0_], K, \
                   &As[b_][r0_ * 64], lane); \
        } \
        { \
            const int r0_ = w * 16 + (p_) * 8; \
            stage8(&Wqkv[(size_t)(tileN + r0_) * K + k0_], K, \
                   &Bs[b_][r0_ * 64], lane); \
        } \
    } while (0)

    // prologue: tiles 0 and 1 fully in flight (12 loads/thread)
    STAGE_HALF(0, 0, 0); STAGE_HALF(0, 0, 1);
    STAGE_HALF(1, 1, 0); STAGE_HALF(1, 1, 1);

    const int NT = K >> 6;               // 16
#pragma unroll 1
    for (int t = 0; t < NT; ++t) {
        if (t + 1 < NT) asm volatile("s_waitcnt vmcnt(6)" ::: "memory");
        else            asm volatile("s_waitcnt vmcnt(0)" ::: "memory");
        __builtin_amdgcn_s_barrier();
        asm volatile("" ::: "memory");   // compiler fence: no read hoisting

        const bf16_t* as = &As[t % 3][0];
        const bf16_t* bs = &Bs[t % 3][0];
        const int nb = (t + 2) % 3;

#pragma unroll
        for (int p = 0; p < 2; p++) {
            const int phys = ((p * 4 + quad) ^ par8) << 3;
            bf16x8 af[4], bf[4];
#pragma unroll
            for (int i = 0; i < 4; i++)
                af[i] = *(bf16x8*)&as[(wm + i * 16 + l15) * 64 + phys];
#pragma unroll
            for (int j = 0; j < 4; j++)
                bf[j] = *(bf16x8*)&bs[(wn + j * 16 + l15) * 64 + phys];
            if (t + 2 < NT) STAGE_HALF(t + 2, nb, p);
            __builtin_amdgcn_s_barrier();
            asm volatile("s_waitcnt lgkmcnt(0)" ::: "memory");
            __builtin_amdgcn_sched_barrier(0);
            __builtin_amdgcn_s_setprio(1);
#pragma unroll
            for (int i = 0; i < 4; i++)
#pragma unroll
                for (int j = 0; j < 4; j++)
                    acc[i][j] = __builtin_amdgcn_mfma_f32_16x16x32_bf16(
                        af[i], bf[j], acc[i][j], 0, 0, 0);
            __builtin_amdgcn_s_setprio(0);
            if (p == 0) __builtin_amdgcn_s_barrier();
        }
    }
#undef STAGE_HALF

    const int region = tileN >> 10;    // 0=Q, 1=K, 2=V (block-uniform)
    const float osc = (region == 0) ? 0.125f * 1.44269504f : 1.0f;
#pragma unroll
    for (int i = 0; i < 4; i++) {
        const int row = tileM + wm + i * 16 + quad * 4;
#pragma unroll
        for (int j = 0; j < 4; j++) {
            const int ncol = tileN + wn + j * 16 + l15;
            if (region == 2) {
                const int cl = ncol - 2048;
                const int h = cl >> 6, d = cl & 63;
                const int bb = row >> 11, tloc = row & (TT - 1);
                bf16x4 pk;
#pragma unroll
                for (int r = 0; r < 4; r++) pk[r] = (bf16_t)acc[i][j][r];
                *(bf16x4*)&Vto[(((size_t)bb * HH + h) * HD + d) * TT + tloc] = pk;
            } else {
                bf16_t* dst = (region == 0) ? Qo : Ko;
                const int cl = ncol & 1023;
#pragma unroll
                for (int r = 0; r < 4; r++)
                    dst[(size_t)(row + r) * DDIM + cl] = (bf16_t)(acc[i][j][r] * osc);
            }
        }
    }
}

// ---------------------------------------------------------------------------
// Output-projection GEMM v3 (r5-proven, unchanged): 128x128 tile, 2-phase
// double-buffer, full-row XOR swizzle, fp32 epilogue. Grid (8, M/128).
// ---------------------------------------------------------------------------
__global__ __launch_bounds__(256) void gemm_out(
    const bf16_t* __restrict__ A, const bf16_t* __restrict__ Bm,
    float* __restrict__ C, int M, int N, int K)
{
    __shared__ alignas(16) bf16_t As[2][128 * 64];
    __shared__ alignas(16) bf16_t Bs[2][128 * 64];

    const int tid  = threadIdx.x;
    const int lane = tid & 63;
    const int w    = tid >> 6;
    const int quad = lane >> 4;
    const int l15  = lane & 15;
    const int wm   = (w >> 1) * 64;
    const int wn   = (w & 1) * 64;

    const int nwg = gridDim.x * gridDim.y;
    const int cpx = nwg >> 3;
    int id = blockIdx.y * gridDim.x + blockIdx.x;
    id = (id & 7) * cpx + (id >> 3);
    const int tileN = (id % 8) * 128;      // gridDim.x == 8
    const int tileM = (id / 8) * 128;

    const f32x4 vzero = {0.f, 0.f, 0.f, 0.f};
    f32x4 acc[4][4];
#pragma unroll
    for (int i = 0; i < 4; i++)
#pragma unroll
        for (int j = 0; j < 4; j++) acc[i][j] = vzero;

    const int par8 = l15 & 7;

#pragma unroll
    for (int q = 0; q < 4; q++) {
        const int r0 = w * 32 + q * 8;
        stage8(&A[(size_t)(tileM + r0) * K], K, &As[0][r0 * 64], lane);
        stage8(&Bm[(size_t)(tileN + r0) * K], K, &Bs[0][r0 * 64], lane);
    }
    __syncthreads();

    const int NT = K >> 6;
    for (int t = 0; t < NT; ++t) {
        const int cur = t & 1;
        if (t + 1 < NT) {
            const int k0 = (t + 1) << 6;
#pragma unroll
            for (int q = 0; q < 4; q++) {
                const int r0 = w * 32 + q * 8;
                stage8(&A[(size_t)(tileM + r0) * K + k0], K,
                       &As[cur ^ 1][r0 * 64], lane);
                stage8(&Bm[(size_t)(tileN + r0) * K + k0], K,
                       &Bs[cur ^ 1][r0 * 64], lane);
            }
        }

#pragma unroll
        for (int ss = 0; ss < 2; ss++) {
            const int phys = ((ss * 4 + quad) ^ par8) << 3;
            bf16x8 af[4], bf[4];
#pragma unroll
            for (int i = 0; i < 2; i++) {
                af[i] = *(bf16x8*)&As[cur][(wm + i * 16 + l15) * 64 + phys];
                af[i + 2] = *(bf16x8*)&As[cur][(wm + (i + 2) * 16 + l15) * 64 + phys];
            }
#pragma unroll
            for (int j = 0; j < 4; j++)
                bf[j] = *(bf16x8*)&Bs[cur][(wn + j * 16 + l15) * 64 + phys];
            __builtin_amdgcn_s_setprio(1);
#pragma unroll
            for (int i = 0; i < 4; i++)
#pragma unroll
                for (int j = 0; j < 4; j++)
                    acc[i][j] = __builtin_amdgcn_mfma_f32_16x16x32_bf16(
                        af[i], bf[j], acc[i][j], 0, 0, 0);
            __builtin_amdgcn_s_setprio(0);
        }
        __syncthreads();
    }

#pragma unroll
    for (int i = 0; i < 4; i++) {
#pragma unroll
        for (int r = 0; r < 4; r++) {
            const int row = tileM + wm + i * 16 + quad * 4 + r;
#pragma unroll
            for (int j = 0; j < 4; j++)
                C[(size_t)row * N + tileN + wn + j * 16 + l15] = acc[i][j][r];
        }
    }
}

// ---------------------------------------------------------------------------
// Flash causal attention v12: v11 structure with the spill fixed.
// r10 post-mortem: __launch_bounds__(256,4) forced 64 VGPRs -> ~40 regs of
// live state spilled to scratch -> WRITE_SIZE 16->153 MB, FETCH +15 MB,
// kernel became HBM-bound on its own spills (145us, MfmaUtil 11).
// Fix: (256,3) -> ~85 VGPRs (v10's no-spill allocation), LDS 34 KiB caps
// at 4 but VGPR caps at 3 blocks/CU = 12 waves (+50% TLP vs v10's 8).
// One 128-row strip per block, grid (nbh, 16) = 1024 blocks; longest-first
// (strip = 15 - blockIdx.y); single-buffer Ks/Vt, 2 barriers/tile.
// XCD locality: linear id mod 8 = bh mod 8. T14 reg prefetch + row&7 XOR
// + setprio + pre-folded scale. Y aliases Q (block touches only its strip).
// ---------------------------------------------------------------------------
__global__ __launch_bounds__(256, 3) void attn_causal(
    const bf16_t* __restrict__ Q, const bf16_t* __restrict__ Kg,
    const bf16_t* __restrict__ Vt_g, bf16_t* __restrict__ Y)
{
    __shared__ alignas(16) bf16_t Ks[64 * 64];     // [key][d] XOR-swz
    __shared__ alignas(16) bf16_t Vt[64 * 64];     // [d][key] XOR-swz
    __shared__ alignas(16) bf16_t Ps[4][32 * 72];  // per-wave P, chunk-swz

    const int tid  = threadIdx.x;
    const int lane = tid & 63;
    const int w    = tid >> 6;
    const int quad = lane >> 4;
    const int l15  = lane & 15;
    const int bh   = blockIdx.x;
    const int strip = 15 - blockIdx.y;   // longest strips dispatch first
    const int b = bh >> 4, h = bh & 15;

    const int stg_row = tid >> 3;        // 0..31
    const int stg_c8  = (tid & 7) * 8;
    const int stg_off = stg_row * 64 + ((((tid & 7) ^ (stg_row & 7))) << 3);
    const int par8 = l15 & 7;            // read-side un-XOR

    const f32x4 vzero = {0.f, 0.f, 0.f, 0.f};
    bf16x8 ones;
#pragma unroll
    for (int j = 0; j < 8; j++) ones[j] = (l15 == 0) ? (bf16_t)1.0f : (bf16_t)0.0f;

    const bf16_t* kg0 = &Kg[(size_t)(b * TT + stg_row) * DDIM + h * 64 + stg_c8];
    const bf16_t* vg0 = &Vt_g[((size_t)bh * HD + stg_row) * TT + stg_c8];

    const int qbase = strip * 128;

    bf16x8 qf[2][2];
#pragma unroll
    for (int mi = 0; mi < 2; mi++) {
        const size_t rq =
            (size_t)(b * TT + qbase + w * 32 + mi * 16 + l15) * DDIM + h * 64;
        qf[mi][0] = *(const bf16x8*)&Q[rq + quad * 8];
        qf[mi][1] = *(const bf16x8*)&Q[rq + 32 + quad * 8];
    }

    f32x4 o[2][4], o4[2];
#pragma unroll
    for (int mi = 0; mi < 2; mi++) {
#pragma unroll
        for (int c = 0; c < 4; c++) o[mi][c] = vzero;
        o4[mi] = vzero;
    }

    const int nkt = 2 * strip + 2;

    // T14 prologue: prefetch key-tile 0 into registers
    bf16x8 kreg[2], vreg[2];
#pragma unroll
    for (int p = 0; p < 2; p++) {
        kreg[p] = *(const bf16x8*)&kg0[(size_t)(p * 32) * DDIM];
        vreg[p] = *(const bf16x8*)&vg0[(size_t)(p * 32) * TT];
    }

#pragma unroll 1
    for (int kt = 0; kt < nkt; kt++) {
        const int kbase = kt * 64;
        __syncthreads();                 // readers of prev tile done
#pragma unroll
        for (int p = 0; p < 2; p++) {
            *(bf16x8*)&Ks[stg_off + p * 32 * 64] = kreg[p];
            *(bf16x8*)&Vt[stg_off + p * 32 * 64] = vreg[p];
        }
        if (kt + 1 < nkt) {
            const int nb = (kt + 1) * 64;
#pragma unroll
            for (int p = 0; p < 2; p++) {
                kreg[p] = *(const bf16x8*)&kg0[(size_t)(nb + p * 32) * DDIM];
                vreg[p] = *(const bf16x8*)&vg0[(size_t)(p * 32) * TT + nb];
            }
        }
        __syncthreads();                 // writes visible

        // S = Q·K^T : shared kf reads across both m-fragments
        f32x4 s[2][4];
        __builtin_amdgcn_s_setprio(1);
#pragma unroll
        for (int c = 0; c < 4; c++) {
            const int krow = (c * 16 + l15) * 64;
            bf16x8 kf0 = *(bf16x8*)&Ks[krow + ((quad ^ par8) << 3)];
            bf16x8 kf1 = *(bf16x8*)&Ks[krow + (((4 + quad) ^ par8) << 3)];
#pragma unroll
            for (int mi = 0; mi < 2; mi++) {
                f32x4 t = __builtin_amdgcn_mfma_f32_16x16x32_bf16(
                    qf[mi][0], kf0, vzero, 0, 0, 0);
                s[mi][c] = __builtin_amdgcn_mfma_f32_16x16x32_bf16(
                    qf[mi][1], kf1, t, 0, 0, 0);
            }
        }
        __builtin_amdgcn_s_setprio(0);

        // p = exp2(s) (scale pre-folded into Q); mask near the diagonal
#pragma unroll
        for (int mi = 0; mi < 2; mi++) {
            const int qlow = qbase + w * 32 + mi * 16;
            const bool need = (kbase + 63 > qlow);   // wave-uniform
#pragma unroll
            for (int r = 0; r < 4; r++) {
                const int qrow = qlow + quad * 4 + r;
                const int prow = mi * 16 + quad * 4 + r;
#pragma unroll
                for (int c = 0; c < 4; c++) {
                    float sv = s[mi][c][r];
                    if (need && (kbase + c * 16 + l15 > qrow)) sv = -1e30f;
                    const int pchunk = (c * 2 + (l15 >> 3)) ^ (prow >> 2);
                    Ps[w][prow * 72 + (pchunk << 3) + (l15 & 7)] =
                        (bf16_t)__builtin_amdgcn_exp2f(sv);
                }
            }
        }
        // Ps wave-private: same-wave RAW via lgkmcnt, no barrier.

        // O += P·V ; o4 += P·ones
        __builtin_amdgcn_s_setprio(1);
#pragma unroll
        for (int ss = 0; ss < 2; ss++) {
            bf16x8 pf[2];
#pragma unroll
            for (int mi = 0; mi < 2; mi++) {
                const int m = mi * 16 + l15;
                pf[mi] = *(bf16x8*)&Ps[w][m * 72 +
                                          ((((ss * 4 + quad) ^ (m >> 2)) & 7) << 3)];
            }
#pragma unroll
            for (int c = 0; c < 4; c++) {
                bf16x8 vf = *(bf16x8*)&Vt[(c * 16 + l15) * 64 +
                                          (((ss * 4 + quad) ^ par8) << 3)];
#pragma unroll
                for (int mi = 0; mi < 2; mi++)
                    o[mi][c] = __builtin_amdgcn_mfma_f32_16x16x32_bf16(
                        pf[mi], vf, o[mi][c], 0, 0, 0);
            }
#pragma unroll
            for (int mi = 0; mi < 2; mi++)
                o4[mi] = __builtin_amdgcn_mfma_f32_16x16x32_bf16(
                    pf[mi], ones, o4[mi], 0, 0, 0);
        }
        __builtin_amdgcn_s_setprio(0);
    }

    // epilogue: row-sum lives in lane l15==0 of each quad group
#pragma unroll
    for (int mi = 0; mi < 2; mi++) {
#pragma unroll
        for (int r = 0; r < 4; r++) {
            const float lsum = __shfl(o4[mi][r], lane & 48, 64);
            const float inv = 1.0f / lsum;
            const int q = qbase + w * 32 + mi * 16 + quad * 4 + r;
#pragma unroll
            for (int c = 0; c < 4; c++)
                Y[(size_t)(b * TT + q) * DDIM + h * 64 + c * 16 + l15] =
                    (bf16_t)(o[mi][c][r] * inv);
        }
    }
}

extern "C" void kernel_launch(void* const* d_in, const int* in_sizes, int n_in,
                              void* d_out, int out_size, void* d_ws, size_t ws_size,
                              hipStream_t stream) {
    (void)in_sizes; (void)n_in; (void)out_size;
    const float* x  = (const float*)d_in[0];
    float* out = (float*)d_out;

    const int M = BB * TT;                     // 8192
    const size_t REGION = (size_t)M * DDIM;    // 8M elems
    const size_t WREG   = (size_t)DDIM * DDIM; // 1M elems
    const size_t BATCH  = (size_t)TT * DDIM;   // 2M elems
    bf16_t* ws = (bf16_t*)d_ws;

    if (ws_size >= (72ull << 20)) {
        // Full path: xb(8M) wpk(4M) Qb(8M) Kb(8M) Vtb(8M) = 36M bf16 = 72 MiB.
        bf16_t* xb  = ws;
        bf16_t* wpk = ws + REGION;
        bf16_t* Qb  = wpk + 4 * WREG;
        bf16_t* Kb  = Qb + REGION;
        bf16_t* Vtb = Kb + REGION;

        cvt_f32_bf16<<<1024, 256, 0, stream>>>(x, xb, REGION / 8);
        cvt_wpack<<<512, 256, 0, stream>>>(
            (const float*)d_in[1], (const float*)d_in[2],
            (const float*)d_in[3], (const float*)d_in[4], wpk);

        gemm_qkv<<<dim3(24, M / 256), 512, 0, stream>>>(
            xb, wpk, Qb, Kb, Vtb, M, DDIM);
        attn_causal<<<dim3(BB * HH, 16), 256, 0, stream>>>(Qb, Kb, Vtb, Qb);
        gemm_out<<<dim3(8, M / 128), 256, 0, stream>>>(
            Qb, wpk + 3 * WREG, out, M, DDIM, DDIM);
    } else {
        // Per-batch path: wpk(4M) + xb(2M) + Qb,Kb,Vtb(3x2M) = 12M = 24 MiB.
        bf16_t* wpk = ws;
        bf16_t* xbb = ws + 4 * WREG;
        bf16_t* Qb  = xbb + BATCH;
        bf16_t* Kb  = Qb + BATCH;
        bf16_t* Vtb = Kb + BATCH;

        cvt_wpack<<<512, 256, 0, stream>>>(
            (const float*)d_in[1], (const float*)d_in[2],
            (const float*)d_in[3], (const float*)d_in[4], wpk);

        for (int b = 0; b < BB; b++) {
            const float* x_b = x + (size_t)b * BATCH;
            float* out_b = out + (size_t)b * BATCH;
            cvt_f32_bf16<<<512, 256, 0, stream>>>(x_b, xbb, BATCH / 8);
            gemm_qkv<<<dim3(24, TT / 256), 512, 0, stream>>>(
                xbb, wpk, Qb, Kb, Vtb, TT, DDIM);
            attn_causal<<<dim3(HH, 16), 256, 0, stream>>>(Qb, Kb, Vtb, Qb);
            gemm_out<<<dim3(8, TT / 128), 256, 0, stream>>>(
                Qb, wpk + 3 * WREG, out_b, TT, DDIM, DDIM);
        }
    }
}